// Round 3
// baseline (788.026 us; speedup 1.0000x reference)
//
#include <hip/hip_runtime.h>
#include <hip/hip_bf16.h>

#define TD 10
#define TH 8
#define TW 32
#define HD (TD+2)    // 12
#define HH (TH+2)    // 10
#define HWD (TW+2)   // 34
#define HALO_N (HD*HH*HWD)  // 4080

#define DIM_D 128
#define DIM_H 192
#define DIM_W 192
#define NDT ((DIM_D + TD - 1)/TD)   // 13

#define LOG2E 1.4426950408889634f
#define LN2   0.6931471805599453f

__device__ __forceinline__ float ex2(float x)  { return __builtin_amdgcn_exp2f(x); }
__device__ __forceinline__ float lg2(float x)  { return __builtin_amdgcn_logf(x); }
__device__ __forceinline__ float rcpf_(float x){ return __builtin_amdgcn_rcpf(x); }
__device__ __forceinline__ float fsig(float x) { return rcpf_(1.f + ex2(-LOG2E*x)); }

struct Plane { float u0b,u1b,u2b,s1,s2,s3,u0t,u1t,u2t; };

__device__ __forceinline__ Plane calc_plane(const float2 st[HD][HH][HWD],
                                            int dz, int ty, int tx)
{
    const float S30 = 47.f/256.f, S31 = 162.f/256.f;
    float2 c00=st[dz][ty  ][tx], c01=st[dz][ty  ][tx+1], c02=st[dz][ty  ][tx+2];
    float2 c10=st[dz][ty+1][tx], c11=st[dz][ty+1][tx+1], c12=st[dz][ty+1][tx+2];
    float2 c20=st[dz][ty+2][tx], c21=st[dz][ty+2][tx+1], c22=st[dz][ty+2][tx+2];
    Plane P;
    P.u0b = c11.x;
    P.u1b = (c01.x + c21.x) + (c10.x + c12.x);
    P.u2b = (c00.x + c02.x) + (c20.x + c22.x);
    P.s1  = S30*((c00.x - c02.x) + (c20.x - c22.x)) + S31*(c10.x - c12.x);
    P.s2  = S30*((c00.x - c20.x) + (c02.x - c22.x)) + S31*(c01.x - c21.x);
    P.s3  = (S31*S31)*P.u0b + (S30*S31)*P.u1b + (S30*S30)*P.u2b;
    P.u0t = c11.y;
    P.u1t = (c01.y + c21.y) + (c10.y + c12.y);
    P.u2t = (c00.y + c02.y) + (c20.y + c22.y);
    return P;
}

__global__ __launch_bounds__(256, 5) void lumen_main(
    const float* __restrict__ x_in, const float* __restrict__ y_out,
    const float* __restrict__ y_tg, double* __restrict__ gacc,
    float* __restrict__ dice_i, float* __restrict__ dice_c)
{
    __shared__ float2 st[HD][HH][HWD];   // 32,640 B; reused as scratch post-loop

    const int tid = threadIdx.x;
    const int b  = blockIdx.z / NDT;
    const int dt = blockIdx.z % NDT;
    const int d0 = dt * TD;
    const int h0 = blockIdx.y * TH;
    const int w0 = blockIdx.x * TW;
    const unsigned base = (unsigned)b * (unsigned)(DIM_D*DIM_H*DIM_W);

    // ---- halo staging: (yb, tg) interleaved float2 ----
    for (int l = tid; l < HALO_N; l += 256) {
        int dz = l / (HH*HWD);
        int r  = l - dz*(HH*HWD);
        int dy = r / HWD;
        int dx = r - dy*HWD;
        int gd = d0 - 1 + dz, gh = h0 - 1 + dy, gw = w0 - 1 + dx;
        bool ok = ((unsigned)gd < (unsigned)DIM_D) &&
                  ((unsigned)gh < (unsigned)DIM_H) &&
                  ((unsigned)gw < (unsigned)DIM_W);
        float yb = 0.f, tg = 0.f;
        if (ok) {
            unsigned gi = base + ((unsigned)gd*DIM_H + (unsigned)gh)*DIM_W + (unsigned)gw;
            float yo = y_out[gi];
            tg = y_tg[gi];
            yb = fsig(200.f*fsig(yo) - 100.f);
        }
        ((float2*)st)[l] = make_float2(yb, tg);
    }
    __syncthreads();

    const int ty = tid >> 5, tx = tid & 31;
    const int gh = h0 + ty, gw = w0 + tx;
    const int dlim = min(TD, DIM_D - d0);

    const float KC1 = 4.5399929762484854e-05f, KC2 = 7.2135410e-07f, KC3 = 3.0047e-08f;
    const float L0 = -88.f/26.f, L1 = 6.f/26.f, L2 = 3.f/26.f, L3 = 2.f/26.f;
    const float S30 = 47.f/256.f, S31 = 162.f/256.f;

    const float nh = 2.f - (gh==0) - (gh==DIM_H-1);
    const float nw = 2.f - (gw==0) - (gw==DIM_W-1);
    const float shw = nh + nw, phw = nh * nw;
    const float Tn1 = 1.f + KC1*(1.f+shw) + KC2*(shw+phw) + KC3*phw;
    const float Tn2 = 1.f + KC1*(2.f+shw) + KC2*(2.f*shw+phw) + KC3*(2.f*phw);

    const unsigned PL = DIM_H*DIM_W;
    const unsigned rowoff = base + ((unsigned)gh)*DIM_W + (unsigned)gw;

    float x_cur  = x_in [rowoff + (unsigned)d0*PL];
    float yo_cur = y_out[rowoff + (unsigned)d0*PL];

    float a_ce=0, a_tz=0, a_pzt=0, a_itzi=0, a_ipzti=0, a_yp=0, a_ytg=0;
    float a_y1y2=0, a_y1=0;
    float a_yS1=0, a_ySx=0, a_ySxx=0, a_y4S1=0, a_y4Sx=0, a_y4Sxx=0;
    float dIi=0, dCc=0;

    Plane P[3];
    P[0] = calc_plane(st, 0, ty, tx);
    P[1] = calc_plane(st, 1, ty, tx);

    #pragma unroll
    for (int td = 0; td < TD; ++td) {
        // 1-deep software pipeline for next-depth center loads (clamped)
        int gdn = min(d0 + td + 1, DIM_D-1);
        float x_nxt  = x_in [rowoff + (unsigned)gdn*PL];
        float yo_nxt = y_out[rowoff + (unsigned)gdn*PL];

        P[(td+2)%3] = calc_plane(st, td+2, ty, tx);

        if (td < dlim) {
            const Plane& A = P[td%3];
            const Plane& B = P[(td+1)%3];
            const Plane& C = P[(td+2)%3];

            const int gd = d0 + td;
            float T = (gd==0 || gd==DIM_D-1) ? Tn1 : Tn2;

            float sb0 = A.u0b + C.u0b, sb1 = A.u1b + C.u1b, sb2 = A.u2b + C.u2b;
            float st0 = A.u0t + C.u0t, st1 = A.u1t + C.u1t, st2 = A.u2t + C.u2t;

            float acx = B.u0b + KC1*(B.u1b + sb0) + KC2*(B.u2b + sb1) + KC3*sb2;
            float act = B.u0t + KC1*(B.u1t + st0) + KC2*(B.u2t + st1) + KC3*st2;
            float al  = L0*B.u0b + L1*(B.u1b + sb0) + L2*(B.u2b + sb1) + L3*sb2;

            float a1 = S30*(A.s1 + C.s1) + S31*B.s1;
            float a2 = S30*(A.s2 + C.s2) + S31*B.s2;
            float a3 = A.s3 - C.s3;

            float ybc = B.u0b;
            float t   = B.u0t;
            float yo  = yo_cur;
            float x   = x_cur;
            float yp  = fsig(yo);

            // CE (stable BCE-with-logits), log2-space
            float q = ex2(-LOG2E*fabsf(yo));
            a_ce += fmaxf(yo, 0.f) - yo*t + LN2*lg2(1.f + q);

            dIi += yp*t;
            dCc += yp + t;

            // DT terms; conv(1-x) = T - conv(x)
            float l2a  = lg2(acx + 1e-6f);
            float z    = -0.1f*LN2*l2a;
            float ztg  = -0.1f*LN2*lg2(act + 1e-6f);
            float zinv = -0.1f*LN2*lg2((T - acx) + 1e-6f);
            float ztgi = -0.1f*LN2*lg2((T - act) + 1e-6f);
            a_tz    += t*z;
            a_pzt   += yp*ztg;
            a_itzi  += (1.f - t)*zinv;
            a_ipzti += (1.f - yp)*ztgi;
            a_yp    += yp;
            a_ytg   += t;

            // ACE S-term
            float y1 = fsig(200.f*al - 100.f);
            float y2 = __builtin_amdgcn_sqrtf(a1*a1 + a2*a2 + a3*a3 + 1e-6f);
            a_y1y2 += y1*y2;
            a_y1   += y1;

            // y4 = sigma(200z - 20) = rcp(1 + 2^(20*l2a + 20*log2e))
            float y4 = rcpf_(1.f + ex2(20.f*l2a + 28.853900817779268f));
            a_yS1  += ybc;  a_ySx  += ybc*x;  a_ySxx  += ybc*x*x;
            a_y4S1 += y4;   a_y4Sx += y4*x;   a_y4Sxx += y4*x*x;
        }
        x_cur = x_nxt; yo_cur = yo_nxt;
    }

    // fold dice across the wave's two ty rows: lanes<32 hold per-tx sums
    dIi += __shfl_xor(dIi, 32);
    dCc += __shfl_xor(dCc, 32);

    float v[15] = {a_ce, a_tz, a_pzt, a_itzi, a_ipzti, a_yp, a_ytg, a_y1y2, a_y1,
                   a_yS1, a_ySx, a_ySxx, a_y4S1, a_y4Sx, a_y4Sxx};
    #pragma unroll
    for (int k = 0; k < 15; ++k) {
        #pragma unroll
        for (int s = 32; s > 0; s >>= 1) v[k] += __shfl_xor(v[k], s);
    }

    __syncthreads();                      // all LDS plane reads complete
    float* sl = (float*)st;               // alias dead plane buffer
    if (tid < 64) sl[tid] = 0.f;          // [0..31]=dice_i, [32..63]=dice_c
    __syncthreads();

    int wid = tid >> 6, lane = tid & 63;
    if (lane < 32) {
        atomicAdd(&sl[lane],      dIi);
        atomicAdd(&sl[32 + lane], dCc);
    }
    if (lane == 0) {
        #pragma unroll
        for (int k = 0; k < 15; ++k) sl[64 + wid*16 + k] = v[k];
    }
    __syncthreads();

    if (tid < 15) {
        float s = sl[64+tid] + sl[80+tid] + sl[96+tid] + sl[112+tid];
        int gidx = (tid < 9) ? tid : (9 + (tid - 9)*2 + b);
        atomicAdd(&gacc[gidx], (double)s);
    }
    if (tid < 32) {
        atomicAdd(&dice_i[b*DIM_W + w0 + tid], sl[tid]);
        atomicAdd(&dice_c[b*DIM_W + w0 + tid], sl[32 + tid]);
    }
}

__global__ __launch_bounds__(256) void lumen_final(
    const double* __restrict__ gacc,
    const float* __restrict__ dice_i, const float* __restrict__ dice_c,
    const float* __restrict__ gamma_ace, float* __restrict__ out)
{
    __shared__ float red[4];
    int tid = threadIdx.x;
    float s = 0.f;
    for (int i = tid; i < 2*DIM_W; i += 256) {
        float I = dice_i[i], C = dice_c[i];
        s += 1.f - 2.f*I/(C + 1e-6f);
    }
    #pragma unroll
    for (int sh = 32; sh > 0; sh >>= 1) s += __shfl_xor(s, sh);
    if ((tid & 63) == 0) red[tid >> 6] = s;
    __syncthreads();
    if (tid == 0) {
        double dice_sum = (double)red[0] + red[1] + red[2] + red[3];
        double loss_dice = dice_sum / (2.0*DIM_W);
        const double Nb = (double)DIM_D * DIM_H * DIM_W;
        const double Nt = 2.0 * Nb;
        const double eps = 1e-6;
        double loss_ce = gacc[0]/Nt;
        double dl1 = (gacc[1]/Nt) / ((gacc[6]/Nt) + eps);
        double dl2 = (gacc[2]/Nt) / ((gacc[5]/Nt) + eps);
        double dl3 = (gacc[3]/Nt) / (((Nt - gacc[6])/Nt) + eps);
        double dl4 = (gacc[4]/Nt) / (((Nt - gacc[5])/Nt) + eps);
        double loss_dt = dl1 + dl2 + dl3 + dl4;
        double E1n = 0.0, E2n = 0.0;
        for (int bb = 0; bb < 2; ++bb) {
            double S1 = gacc[9+bb],  Sx = gacc[11+bb], Sxx = gacc[13+bb];
            double l1 = (Sx/Nb) / ((S1/Nb) + eps);
            E1n += Sxx - 2.0*l1*Sx + l1*l1*S1;
            double Q1 = gacc[15+bb], Qx = gacc[17+bb], Qxx = gacc[19+bb];
            double l2 = (Qx/Nb) / ((Q1/Nb) + eps);
            E2n += Qxx - 2.0*l2*Qx + l2*l2*Q1;
        }
        double E1 = (E1n/Nt) / (((gacc[9]+gacc[10])/Nt) + eps);
        double E2 = (E2n/Nt) / (((gacc[15]+gacc[16])/Nt) + eps);
        double S  = (gacc[7]/Nt) / ((gacc[8]/Nt) + eps);
        double loss_ace = E1 + E2 + (double)gamma_ace[0]*S;
        out[0] = (float)(loss_ce + loss_dice + 0.1*loss_dt + 0.1*loss_ace);
    }
}

extern "C" void kernel_launch(void* const* d_in, const int* in_sizes, int n_in,
                              void* d_out, int out_size, void* d_ws, size_t ws_size,
                              hipStream_t stream) {
    const float* x_in  = (const float*)d_in[0];
    const float* y_out = (const float*)d_in[1];
    const float* y_tg  = (const float*)d_in[2];
    const float* gamma = (const float*)d_in[4];
    float* out = (float*)d_out;

    double* gacc  = (double*)d_ws;                       // 21 doubles
    float* dice_i = (float*)((char*)d_ws + 512);         // 384 floats
    float* dice_c = (float*)((char*)d_ws + 2048);        // 384 floats

    hipMemsetAsync(d_ws, 0, 4096, stream);

    dim3 grid(DIM_W/TW, DIM_H/TH, 2*NDT);
    lumen_main<<<grid, 256, 0, stream>>>(x_in, y_out, y_tg, gacc, dice_i, dice_c);
    lumen_final<<<1, 256, 0, stream>>>(gacc, dice_i, dice_c, gamma, out);
}

// Round 4
// 132.273 us; speedup vs baseline: 5.9576x; 5.9576x over previous
//
#include <hip/hip_runtime.h>
#include <hip/hip_bf16.h>

#define TD 10
#define TH 8
#define TW 32
#define HD (TD+2)    // 12
#define HH (TH+2)    // 10
#define HWD (TW+2)   // 34
#define HALO_N (HD*HH*HWD)  // 4080

#define DIM_D 128
#define DIM_H 192
#define DIM_W 192
#define NDT ((DIM_D + TD - 1)/TD)   // 13

#define LOG2E 1.4426950408889634f
#define LN2   0.6931471805599453f

__device__ __forceinline__ float ex2(float x)  { return __builtin_amdgcn_exp2f(x); }
__device__ __forceinline__ float lg2(float x)  { return __builtin_amdgcn_logf(x); }
__device__ __forceinline__ float rcpf_(float x){ return __builtin_amdgcn_rcpf(x); }
// sigmoid(x) = rcp(1 + 2^(-log2e * x))
__device__ __forceinline__ float fsig(float x) { return rcpf_(1.f + ex2(-LOG2E*x)); }

struct Plane { float u0b,u1b,u2b,s1,s2,s3,u0t,u1t,u2t; };

__device__ __forceinline__ Plane calc_plane(const float2 st[HD][HH][HWD],
                                            int dz, int ty, int tx)
{
    const float S30 = 47.f/256.f, S31 = 162.f/256.f;
    float2 c00=st[dz][ty  ][tx], c01=st[dz][ty  ][tx+1], c02=st[dz][ty  ][tx+2];
    float2 c10=st[dz][ty+1][tx], c11=st[dz][ty+1][tx+1], c12=st[dz][ty+1][tx+2];
    float2 c20=st[dz][ty+2][tx], c21=st[dz][ty+2][tx+1], c22=st[dz][ty+2][tx+2];
    Plane P;
    P.u0b = c11.x;
    P.u1b = (c01.x + c21.x) + (c10.x + c12.x);
    P.u2b = (c00.x + c02.x) + (c20.x + c22.x);
    P.s1  = S30*((c00.x - c02.x) + (c20.x - c22.x)) + S31*(c10.x - c12.x);
    P.s2  = S30*((c00.x - c20.x) + (c02.x - c22.x)) + S31*(c01.x - c21.x);
    P.s3  = (S31*S31)*P.u0b + (S30*S31)*P.u1b + (S30*S30)*P.u2b;
    P.u0t = c11.y;
    P.u1t = (c01.y + c21.y) + (c10.y + c12.y);
    P.u2t = (c00.y + c02.y) + (c20.y + c22.y);
    return P;
}

__global__ __launch_bounds__(256) void lumen_main(
    const float* __restrict__ x_in, const float* __restrict__ y_out,
    const float* __restrict__ y_tg, double* __restrict__ gacc,
    float* __restrict__ dice_i, float* __restrict__ dice_c)
{
    __shared__ float2 st[HD][HH][HWD];   // 32,640 B; reused as scratch post-loop

    const int tid = threadIdx.x;
    const int b  = blockIdx.z / NDT;
    const int dt = blockIdx.z % NDT;
    const int d0 = dt * TD;
    const int h0 = blockIdx.y * TH;
    const int w0 = blockIdx.x * TW;
    const unsigned base = (unsigned)b * (unsigned)(DIM_D*DIM_H*DIM_W);

    // ---- halo staging: (yb, tg) interleaved float2 ----
    for (int l = tid; l < HALO_N; l += 256) {
        int dz = l / (HH*HWD);
        int r  = l - dz*(HH*HWD);
        int dy = r / HWD;
        int dx = r - dy*HWD;
        int gd = d0 - 1 + dz, gh = h0 - 1 + dy, gw = w0 - 1 + dx;
        bool ok = ((unsigned)gd < (unsigned)DIM_D) &&
                  ((unsigned)gh < (unsigned)DIM_H) &&
                  ((unsigned)gw < (unsigned)DIM_W);
        float yb = 0.f, tg = 0.f;
        if (ok) {
            unsigned gi = base + ((unsigned)gd*DIM_H + (unsigned)gh)*DIM_W + (unsigned)gw;
            float yo = y_out[gi];
            tg = y_tg[gi];
            float yp = fsig(yo);
            yb = rcpf_(1.f + ex2(fmaf(-200.f*LOG2E, yp, 100.f*LOG2E)));
        }
        ((float2*)st)[l] = make_float2(yb, tg);
    }
    __syncthreads();

    const int ty = tid >> 5, tx = tid & 31;
    const int gh = h0 + ty, gw = w0 + tx;
    const int dlim = min(TD, DIM_D - d0);

    const float KC1 = 4.5399929762484854e-05f, KC2 = 7.2135410e-07f, KC3 = 3.0047e-08f;
    const float L0 = -88.f/26.f, L1 = 6.f/26.f, L2 = 3.f/26.f, L3 = 2.f/26.f;
    const float S30 = 47.f/256.f, S31 = 162.f/256.f;

    const float nh = 2.f - (gh==0) - (gh==DIM_H-1);
    const float nw = 2.f - (gw==0) - (gw==DIM_W-1);
    const float shw = nh + nw, phw = nh * nw;
    const float Tn1 = 1.f + KC1*(1.f+shw) + KC2*(shw+phw) + KC3*phw;
    const float Tn2 = 1.f + KC1*(2.f+shw) + KC2*(2.f*shw+phw) + KC3*(2.f*phw);

    const unsigned PL = DIM_H*DIM_W;
    const unsigned rowoff = base + ((unsigned)gh)*DIM_W + (unsigned)gw;

    float a_ce=0, a_tz=0, a_pzt=0, a_itzi=0, a_ipzti=0, a_yp=0, a_ytg=0;
    float a_y1y2=0, a_y1=0;
    float a_yS1=0, a_ySx=0, a_ySxx=0, a_y4S1=0, a_y4Sx=0, a_y4Sxx=0;
    float dIi=0, dCc=0;

    Plane P[3];
    P[0] = calc_plane(st, 0, ty, tx);
    P[1] = calc_plane(st, 1, ty, tx);

    #pragma unroll
    for (int td = 0; td < TD; ++td) {
        P[(td+2)%3] = calc_plane(st, td+2, ty, tx);

        if (td < dlim) {
            const Plane& A = P[td%3];
            const Plane& B = P[(td+1)%3];
            const Plane& C = P[(td+2)%3];

            const int gd = d0 + td;
            const unsigned gi = rowoff + (unsigned)gd*PL;
            float x  = x_in[gi];
            float yo = y_out[gi];

            float T = (gd==0 || gd==DIM_D-1) ? Tn1 : Tn2;

            float sb0 = A.u0b + C.u0b, sb1 = A.u1b + C.u1b, sb2 = A.u2b + C.u2b;
            float st0 = A.u0t + C.u0t, st1 = A.u1t + C.u1t, st2 = A.u2t + C.u2t;

            float acx = B.u0b + KC1*(B.u1b + sb0) + KC2*(B.u2b + sb1) + KC3*sb2;
            float act = B.u0t + KC1*(B.u1t + st0) + KC2*(B.u2t + st1) + KC3*st2;
            float al  = L0*B.u0b + L1*(B.u1b + sb0) + L2*(B.u2b + sb1) + L3*sb2;

            float a1 = S30*(A.s1 + C.s1) + S31*B.s1;
            float a2 = S30*(A.s2 + C.s2) + S31*B.s2;
            float a3 = A.s3 - C.s3;

            float ybc = B.u0b;
            float t   = B.u0t;
            float yp  = fsig(yo);

            // CE (stable BCE-with-logits), log2-space
            float q = ex2(-LOG2E*fabsf(yo));
            a_ce += fmaxf(yo, 0.f) - yo*t + LN2*lg2(1.f + q);

            dIi += yp*t;
            dCc += yp + t;

            // DT terms; conv(1-x) = T - conv(x)
            float l2a  = lg2(acx + 1e-6f);
            float z    = -0.1f*LN2*l2a;
            float ztg  = -0.1f*LN2*lg2(act + 1e-6f);
            float zinv = -0.1f*LN2*lg2((T - acx) + 1e-6f);
            float ztgi = -0.1f*LN2*lg2((T - act) + 1e-6f);
            a_tz    += t*z;
            a_pzt   += yp*ztg;
            a_itzi  += (1.f - t)*zinv;
            a_ipzti += (1.f - yp)*ztgi;
            a_yp    += yp;
            a_ytg   += t;

            // ACE S-term
            float y1 = rcpf_(1.f + ex2(fmaf(-200.f*LOG2E, al, 100.f*LOG2E)));
            float y2 = __builtin_amdgcn_sqrtf(a1*a1 + a2*a2 + a3*a3 + 1e-6f);
            a_y1y2 += y1*y2;
            a_y1   += y1;

            // y4 = sigma(200z - 20) = rcp(1 + 2^(20*l2a + 20*log2e))
            float y4 = rcpf_(1.f + ex2(fmaf(20.f, l2a, 28.853900817779268f)));
            a_yS1  += ybc;  a_ySx  += ybc*x;  a_ySxx  += ybc*x*x;
            a_y4S1 += y4;   a_y4Sx += y4*x;   a_y4Sxx += y4*x*x;
        }
    }

    // fold dice across the wave's two ty rows: lanes<32 hold per-tx sums
    dIi += __shfl_xor(dIi, 32);
    dCc += __shfl_xor(dCc, 32);

    float v[15] = {a_ce, a_tz, a_pzt, a_itzi, a_ipzti, a_yp, a_ytg, a_y1y2, a_y1,
                   a_yS1, a_ySx, a_ySxx, a_y4S1, a_y4Sx, a_y4Sxx};
    #pragma unroll
    for (int k = 0; k < 15; ++k) {
        #pragma unroll
        for (int s = 32; s > 0; s >>= 1) v[k] += __shfl_xor(v[k], s);
    }

    __syncthreads();                      // all LDS plane reads complete
    float* sl = (float*)st;               // alias dead plane buffer
    if (tid < 64) sl[tid] = 0.f;          // [0..31]=dice_i, [32..63]=dice_c
    __syncthreads();

    int wid = tid >> 6, lane = tid & 63;
    if (lane < 32) {
        atomicAdd(&sl[lane],      dIi);
        atomicAdd(&sl[32 + lane], dCc);
    }
    if (lane == 0) {
        #pragma unroll
        for (int k = 0; k < 15; ++k) sl[64 + wid*16 + k] = v[k];
    }
    __syncthreads();

    if (tid < 15) {
        float s = sl[64+tid] + sl[80+tid] + sl[96+tid] + sl[112+tid];
        int gidx = (tid < 9) ? tid : (9 + (tid - 9)*2 + b);
        atomicAdd(&gacc[gidx], (double)s);
    }
    if (tid < 32) {
        atomicAdd(&dice_i[b*DIM_W + w0 + tid], sl[tid]);
        atomicAdd(&dice_c[b*DIM_W + w0 + tid], sl[32 + tid]);
    }
}

__global__ __launch_bounds__(256) void lumen_final(
    const double* __restrict__ gacc,
    const float* __restrict__ dice_i, const float* __restrict__ dice_c,
    const float* __restrict__ gamma_ace, float* __restrict__ out)
{
    __shared__ float red[4];
    int tid = threadIdx.x;
    float s = 0.f;
    for (int i = tid; i < 2*DIM_W; i += 256) {
        float I = dice_i[i], C = dice_c[i];
        s += 1.f - 2.f*I/(C + 1e-6f);
    }
    #pragma unroll
    for (int sh = 32; sh > 0; sh >>= 1) s += __shfl_xor(s, sh);
    if ((tid & 63) == 0) red[tid >> 6] = s;
    __syncthreads();
    if (tid == 0) {
        double dice_sum = (double)red[0] + red[1] + red[2] + red[3];
        double loss_dice = dice_sum / (2.0*DIM_W);
        const double Nb = (double)DIM_D * DIM_H * DIM_W;
        const double Nt = 2.0 * Nb;
        const double eps = 1e-6;
        double loss_ce = gacc[0]/Nt;
        double dl1 = (gacc[1]/Nt) / ((gacc[6]/Nt) + eps);
        double dl2 = (gacc[2]/Nt) / ((gacc[5]/Nt) + eps);
        double dl3 = (gacc[3]/Nt) / (((Nt - gacc[6])/Nt) + eps);
        double dl4 = (gacc[4]/Nt) / (((Nt - gacc[5])/Nt) + eps);
        double loss_dt = dl1 + dl2 + dl3 + dl4;
        double E1n = 0.0, E2n = 0.0;
        for (int bb = 0; bb < 2; ++bb) {
            double S1 = gacc[9+bb],  Sx = gacc[11+bb], Sxx = gacc[13+bb];
            double l1 = (Sx/Nb) / ((S1/Nb) + eps);
            E1n += Sxx - 2.0*l1*Sx + l1*l1*S1;
            double Q1 = gacc[15+bb], Qx = gacc[17+bb], Qxx = gacc[19+bb];
            double l2 = (Qx/Nb) / ((Q1/Nb) + eps);
            E2n += Qxx - 2.0*l2*Qx + l2*l2*Q1;
        }
        double E1 = (E1n/Nt) / (((gacc[9]+gacc[10])/Nt) + eps);
        double E2 = (E2n/Nt) / (((gacc[15]+gacc[16])/Nt) + eps);
        double S  = (gacc[7]/Nt) / ((gacc[8]/Nt) + eps);
        double loss_ace = E1 + E2 + (double)gamma_ace[0]*S;
        out[0] = (float)(loss_ce + loss_dice + 0.1*loss_dt + 0.1*loss_ace);
    }
}

extern "C" void kernel_launch(void* const* d_in, const int* in_sizes, int n_in,
                              void* d_out, int out_size, void* d_ws, size_t ws_size,
                              hipStream_t stream) {
    const float* x_in  = (const float*)d_in[0];
    const float* y_out = (const float*)d_in[1];
    const float* y_tg  = (const float*)d_in[2];
    const float* gamma = (const float*)d_in[4];
    float* out = (float*)d_out;

    double* gacc  = (double*)d_ws;                       // 21 doubles
    float* dice_i = (float*)((char*)d_ws + 512);         // 384 floats
    float* dice_c = (float*)((char*)d_ws + 2048);        // 384 floats

    hipMemsetAsync(d_ws, 0, 4096, stream);

    dim3 grid(DIM_W/TW, DIM_H/TH, 2*NDT);
    lumen_main<<<grid, 256, 0, stream>>>(x_in, y_out, y_tg, gacc, dice_i, dice_c);
    lumen_final<<<1, 256, 0, stream>>>(gacc, dice_i, dice_c, gamma, out);
}

// Round 5
// 103.050 us; speedup vs baseline: 7.6470x; 1.2836x over previous
//
#include <hip/hip_runtime.h>
#include <hip/hip_bf16.h>

#define TH 8
#define TW 32
#define DC 32
#define PH (TH+2)    // 10
#define PW (TW+2)    // 34
#define PN (PH*PW)   // 340

#define DIM_D 128
#define DIM_H 192
#define DIM_W 192

#define LOG2E 1.4426950408889634f
#define LN2   0.6931471805599453f

__device__ __forceinline__ float ex2(float x){ return __builtin_amdgcn_exp2f(x); }
__device__ __forceinline__ float lg2(float x){ return __builtin_amdgcn_logf(x); }
__device__ __forceinline__ float rcpf_(float x){ return __builtin_amdgcn_rcpf(x); }

struct Plane { float u0b,u1b,u2b,s1,s2,u0t,u1t,u2t; };

__device__ __forceinline__ Plane calc_plane(const float2* __restrict__ sp, int ty, int tx)
{
    const float S30 = 47.f/256.f, S31 = 162.f/256.f;
    float2 c00=sp[(ty  )*PW+tx], c01=sp[(ty  )*PW+tx+1], c02=sp[(ty  )*PW+tx+2];
    float2 c10=sp[(ty+1)*PW+tx], c11=sp[(ty+1)*PW+tx+1], c12=sp[(ty+1)*PW+tx+2];
    float2 c20=sp[(ty+2)*PW+tx], c21=sp[(ty+2)*PW+tx+1], c22=sp[(ty+2)*PW+tx+2];
    Plane P;
    P.u0b = c11.x;
    P.u1b = (c01.x + c21.x) + (c10.x + c12.x);
    P.u2b = (c00.x + c02.x) + (c20.x + c22.x);
    P.s1  = S30*((c00.x - c02.x) + (c20.x - c22.x)) + S31*(c10.x - c12.x);
    P.s2  = S30*((c00.x - c20.x) + (c02.x - c22.x)) + S31*(c01.x - c21.x);
    P.u0t = c11.y;
    P.u1t = (c01.y + c21.y) + (c10.y + c12.y);
    P.u2t = (c00.y + c02.y) + (c20.y + c22.y);
    return P;
}

__global__ __launch_bounds__(256) void lumen_main(
    const float* __restrict__ x_in, const float* __restrict__ y_out,
    const float* __restrict__ y_tg, double* __restrict__ gacc,
    float* __restrict__ dice_i, float* __restrict__ dice_c)
{
    __shared__ float2 ring[4][PN];   // 10,880 B; aliased as scratch post-loop

    const int tid = threadIdx.x;
    const int b  = blockIdx.z >> 2;
    const int d0 = (blockIdx.z & 3) * DC;
    const int h0 = blockIdx.y * TH;
    const int w0 = blockIdx.x * TW;
    const unsigned base = (unsigned)b * (unsigned)(DIM_D*DIM_H*DIM_W);
    const unsigned PL = DIM_H*DIM_W;

    // ---- staging map: thread handles halo elems tid and tid+256 ----
    const int l1v = tid + 256;
    const int dy0 = tid / PW, dx0 = tid - dy0*PW;
    const int dy1 = l1v / PW, dx1 = l1v - dy1*PW;
    const int sgh0 = h0-1+dy0, sgw0 = w0-1+dx0;
    const int sgh1 = h0-1+dy1, sgw1 = w0-1+dx1;
    const bool w1  = (l1v < PN);
    const bool ok0 = ((unsigned)sgh0 < (unsigned)DIM_H) && ((unsigned)sgw0 < (unsigned)DIM_W);
    const bool ok1 = w1 && ((unsigned)sgh1 < (unsigned)DIM_H) && ((unsigned)sgw1 < (unsigned)DIM_W);
    const unsigned soff0 = ok0 ? (unsigned)(sgh0*DIM_W + sgw0) : 0u;
    const unsigned soff1 = ok1 ? (unsigned)(sgh1*DIM_W + sgw1) : 0u;

    float ld_yo0, ld_tg0, ld_yo1, ld_tg1;

    auto LOADP = [&](int p){
        if ((unsigned)p < (unsigned)DIM_D) {       // uniform branch
            const unsigned pb = base + (unsigned)p*PL;
            float a = y_out[pb + soff0], c = y_tg[pb + soff0];
            float e = y_out[pb + soff1], f = y_tg[pb + soff1];
            ld_yo0 = ok0 ? a : -1e30f;  ld_tg0 = ok0 ? c : 0.f;
            ld_yo1 = ok1 ? e : -1e30f;  ld_tg1 = ok1 ? f : 0.f;
        } else {
            ld_yo0 = -1e30f; ld_tg0 = 0.f; ld_yo1 = -1e30f; ld_tg1 = 0.f;
        }
    };
    // yo=-1e30 -> yp=0 -> yb = rcp(1+2^144) = 0  (zero padding falls out)
    auto WRITEP = [&](int slot){
        float yp0 = rcpf_(1.f + ex2(-LOG2E*ld_yo0));
        float yb0 = rcpf_(1.f + ex2(fmaf(-200.f*LOG2E, yp0, 100.f*LOG2E)));
        ring[slot][tid] = make_float2(yb0, ld_tg0);
        if (w1) {
            float yp1 = rcpf_(1.f + ex2(-LOG2E*ld_yo1));
            float yb1 = rcpf_(1.f + ex2(fmaf(-200.f*LOG2E, yp1, 100.f*LOG2E)));
            ring[slot][l1v] = make_float2(yb1, ld_tg1);
        }
    };

    const int ty = tid >> 5, tx = tid & 31;
    const int gh = h0 + ty, gw = w0 + tx;
    const unsigned cen = base + (unsigned)(gh*DIM_W + gw);

    const float KC1 = 4.5399929762484854e-05f, KC2 = 7.2135410e-07f, KC3 = 3.0047e-08f;
    const float L0 = -88.f/26.f, L1 = 6.f/26.f, L2 = 3.f/26.f, L3 = 2.f/26.f;
    const float S30 = 47.f/256.f, S31 = 162.f/256.f;

    const float nhh = 2.f - (gh==0) - (gh==DIM_H-1);
    const float nww = 2.f - (gw==0) - (gw==DIM_W-1);
    const float shw = nhh + nww, phw = nhh * nww;
    const float Tn1 = 1.f + KC1*(1.f+shw) + KC2*(shw+phw) + KC3*phw;
    const float Tn2 = 1.f + KC1*(2.f+shw) + KC2*(2.f*shw+phw) + KC3*(2.f*phw);

    // ---- prologue: planes d0-1, d0, d0+1 staged; d0+2 in regs ----
    LOADP(d0-1); WRITEP(3);
    LOADP(d0  ); WRITEP(0);
    LOADP(d0+1); WRITEP(1);
    LOADP(d0+2);
    float xc  = x_in [cen + (unsigned)d0*PL];
    float yoc = y_out[cen + (unsigned)d0*PL];
    __syncthreads();
    Plane PA = calc_plane(ring[3], ty, tx);
    Plane PB = calc_plane(ring[0], ty, tx);

    float a_ce=0, a_tz=0, a_pzt=0, a_itzi=0, a_ipzti=0, a_yp=0, a_ytg=0;
    float a_y1y2=0, a_y1=0;
    float a_yS1=0, a_ySx=0, a_ySxx=0, a_y4S1=0, a_y4Sx=0, a_y4Sxx=0;
    float dIi=0, dCc=0;

    #pragma unroll 4
    for (int i = 0; i < DC; ++i) {
        const int d = d0 + i;
        WRITEP((i+2)&3);                       // plane d+2 from regs
        __syncthreads();
        LOADP(d+3);                            // prefetch plane d+3 (hidden under math)
        const int dn = min(d+1, DIM_D-1);
        float xn  = x_in [cen + (unsigned)dn*PL];
        float yon = y_out[cen + (unsigned)dn*PL];

        Plane PC = calc_plane(ring[(i+1)&3], ty, tx);   // plane d+1

        float sb0 = PA.u0b + PC.u0b, sb1 = PA.u1b + PC.u1b, sb2 = PA.u2b + PC.u2b;
        float st0 = PA.u0t + PC.u0t, st1 = PA.u1t + PC.u1t, st2 = PA.u2t + PC.u2t;
        float acx = PB.u0b + KC1*(PB.u1b + sb0) + KC2*(PB.u2b + sb1) + KC3*sb2;
        float act = PB.u0t + KC1*(PB.u1t + st0) + KC2*(PB.u2t + st1) + KC3*st2;
        float al  = L0*PB.u0b + L1*(PB.u1b + sb0) + L2*(PB.u2b + sb1) + L3*sb2;
        float a1 = S30*(PA.s1 + PC.s1) + S31*PB.s1;
        float a2 = S30*(PA.s2 + PC.s2) + S31*PB.s2;
        float a3 = (S31*S31)*(PA.u0b - PC.u0b) + (S30*S31)*(PA.u1b - PC.u1b)
                 + (S30*S30)*(PA.u2b - PC.u2b);

        float T = (d==0 || d==DIM_D-1) ? Tn1 : Tn2;
        float t   = PB.u0t;
        float ybc = PB.u0b;

        // CE: one exp2 shared between softplus and sigmoid
        float ayo = fabsf(yoc);
        float e1  = ex2(-LOG2E*ayo);
        float inv = rcpf_(1.f + e1);
        float yp  = (yoc >= 0.f) ? inv : (1.f - inv);
        a_ce += fmaxf(yoc, 0.f) - yoc*t + LN2*lg2(1.f + e1);

        dIi += yp*t;
        dCc += yp + t;

        float l2a = lg2(acx + 1e-6f);
        float z   = -0.1f*LN2*l2a;
        a_tz    += t*z;
        a_pzt   += yp      * (-0.1f*LN2)*lg2(act + 1e-6f);
        a_itzi  += (1.f-t) * (-0.1f*LN2)*lg2((T - acx) + 1e-6f);
        a_ipzti += (1.f-yp)* (-0.1f*LN2)*lg2((T - act) + 1e-6f);
        a_yp    += yp;
        a_ytg   += t;

        float y1 = rcpf_(1.f + ex2(fmaf(-200.f*LOG2E, al, 100.f*LOG2E)));
        float y2 = __builtin_amdgcn_sqrtf(a1*a1 + a2*a2 + a3*a3 + 1e-6f);
        a_y1y2 += y1*y2;
        a_y1   += y1;

        float y4 = rcpf_(1.f + ex2(fmaf(20.f, l2a, 28.853900817779268f)));
        a_yS1  += ybc;  a_ySx  += ybc*xc;  a_ySxx  += ybc*xc*xc;
        a_y4S1 += y4;   a_y4Sx += y4*xc;   a_y4Sxx += y4*xc*xc;

        PA = PB; PB = PC; xc = xn; yoc = yon;
    }

    // fold dice across the wave's two ty rows
    dIi += __shfl_xor(dIi, 32);
    dCc += __shfl_xor(dCc, 32);

    float v[15] = {a_ce, a_tz, a_pzt, a_itzi, a_ipzti, a_yp, a_ytg, a_y1y2, a_y1,
                   a_yS1, a_ySx, a_ySxx, a_y4S1, a_y4Sx, a_y4Sxx};
    #pragma unroll
    for (int k = 0; k < 15; ++k) {
        #pragma unroll
        for (int s = 32; s > 0; s >>= 1) v[k] += __shfl_xor(v[k], s);
    }

    __syncthreads();                 // all ring reads complete
    float* sl = (float*)ring;        // alias dead ring
    if (tid < 64) sl[tid] = 0.f;     // [0..31]=dice_i, [32..63]=dice_c
    __syncthreads();

    int wid = tid >> 6, lane = tid & 63;
    if (lane < 32) {
        atomicAdd(&sl[lane],      dIi);
        atomicAdd(&sl[32 + lane], dCc);
    }
    if (lane == 0) {
        #pragma unroll
        for (int k = 0; k < 15; ++k) sl[64 + wid*16 + k] = v[k];
    }
    __syncthreads();

    if (tid < 15) {
        float s = sl[64+tid] + sl[80+tid] + sl[96+tid] + sl[112+tid];
        int gidx = (tid < 9) ? tid : (9 + (tid - 9)*2 + b);
        atomicAdd(&gacc[gidx], (double)s);
    }
    if (tid < 32) {
        atomicAdd(&dice_i[b*DIM_W + w0 + tid], sl[tid]);
        atomicAdd(&dice_c[b*DIM_W + w0 + tid], sl[32 + tid]);
    }
}

__global__ __launch_bounds__(256) void lumen_final(
    const double* __restrict__ gacc,
    const float* __restrict__ dice_i, const float* __restrict__ dice_c,
    const float* __restrict__ gamma_ace, float* __restrict__ out)
{
    __shared__ float red[4];
    int tid = threadIdx.x;
    float s = 0.f;
    for (int i = tid; i < 2*DIM_W; i += 256) {
        float I = dice_i[i], C = dice_c[i];
        s += 1.f - 2.f*I/(C + 1e-6f);
    }
    #pragma unroll
    for (int sh = 32; sh > 0; sh >>= 1) s += __shfl_xor(s, sh);
    if ((tid & 63) == 0) red[tid >> 6] = s;
    __syncthreads();
    if (tid == 0) {
        double dice_sum = (double)red[0] + red[1] + red[2] + red[3];
        double loss_dice = dice_sum / (2.0*DIM_W);
        const double Nb = (double)DIM_D * DIM_H * DIM_W;
        const double Nt = 2.0 * Nb;
        const double eps = 1e-6;
        double loss_ce = gacc[0]/Nt;
        double dl1 = (gacc[1]/Nt) / ((gacc[6]/Nt) + eps);
        double dl2 = (gacc[2]/Nt) / ((gacc[5]/Nt) + eps);
        double dl3 = (gacc[3]/Nt) / (((Nt - gacc[6])/Nt) + eps);
        double dl4 = (gacc[4]/Nt) / (((Nt - gacc[5])/Nt) + eps);
        double loss_dt = dl1 + dl2 + dl3 + dl4;
        double E1n = 0.0, E2n = 0.0;
        for (int bb = 0; bb < 2; ++bb) {
            double S1 = gacc[9+bb],  Sx = gacc[11+bb], Sxx = gacc[13+bb];
            double l1 = (Sx/Nb) / ((S1/Nb) + eps);
            E1n += Sxx - 2.0*l1*Sx + l1*l1*S1;
            double Q1 = gacc[15+bb], Qx = gacc[17+bb], Qxx = gacc[19+bb];
            double l2 = (Qx/Nb) / ((Q1/Nb) + eps);
            E2n += Qxx - 2.0*l2*Qx + l2*l2*Q1;
        }
        double E1 = (E1n/Nt) / (((gacc[9]+gacc[10])/Nt) + eps);
        double E2 = (E2n/Nt) / (((gacc[15]+gacc[16])/Nt) + eps);
        double S  = (gacc[7]/Nt) / ((gacc[8]/Nt) + eps);
        double loss_ace = E1 + E2 + (double)gamma_ace[0]*S;
        out[0] = (float)(loss_ce + loss_dice + 0.1*loss_dt + 0.1*loss_ace);
    }
}

extern "C" void kernel_launch(void* const* d_in, const int* in_sizes, int n_in,
                              void* d_out, int out_size, void* d_ws, size_t ws_size,
                              hipStream_t stream) {
    const float* x_in  = (const float*)d_in[0];
    const float* y_out = (const float*)d_in[1];
    const float* y_tg  = (const float*)d_in[2];
    const float* gamma = (const float*)d_in[4];
    float* out = (float*)d_out;

    double* gacc  = (double*)d_ws;                       // 21 doubles
    float* dice_i = (float*)((char*)d_ws + 512);         // 384 floats
    float* dice_c = (float*)((char*)d_ws + 2048);        // 384 floats

    hipMemsetAsync(d_ws, 0, 4096, stream);

    dim3 grid(DIM_W/TW, DIM_H/TH, 2*(DIM_D/DC));
    lumen_main<<<grid, 256, 0, stream>>>(x_in, y_out, y_tg, gacc, dice_i, dice_c);
    lumen_final<<<1, 256, 0, stream>>>(gacc, dice_i, dice_c, gamma, out);
}

// Round 8
// 94.198 us; speedup vs baseline: 8.3657x; 1.0940x over previous
//
#include <hip/hip_runtime.h>
#include <hip/hip_bf16.h>

#define TH 8
#define TW 32
#define DC 16
#define PH (TH+2)    // 10
#define PW (TW+2)    // 34
#define PN (PH*PW)   // 340

#define DIM_D 128
#define DIM_H 192
#define DIM_W 192
#define NREP 16      // gacc replicas (atomic spread)

#define LOG2E 1.4426950408889634f
#define LN2   0.6931471805599453f

__device__ __forceinline__ float ex2(float x){ return __builtin_amdgcn_exp2f(x); }
__device__ __forceinline__ float lg2(float x){ return __builtin_amdgcn_logf(x); }
__device__ __forceinline__ float rcpf_(float x){ return __builtin_amdgcn_rcpf(x); }

struct Plane { float u0b,u1b,u2b,s1,s2,u0t,u1t,u2t; };

__device__ __forceinline__ Plane calc_plane(const float2* __restrict__ sp, int ty, int tx)
{
    const float S30 = 47.f/256.f, S31 = 162.f/256.f;
    float2 c00=sp[(ty  )*PW+tx], c01=sp[(ty  )*PW+tx+1], c02=sp[(ty  )*PW+tx+2];
    float2 c10=sp[(ty+1)*PW+tx], c11=sp[(ty+1)*PW+tx+1], c12=sp[(ty+1)*PW+tx+2];
    float2 c20=sp[(ty+2)*PW+tx], c21=sp[(ty+2)*PW+tx+1], c22=sp[(ty+2)*PW+tx+2];
    Plane P;
    P.u0b = c11.x;
    P.u1b = (c01.x + c21.x) + (c10.x + c12.x);
    P.u2b = (c00.x + c02.x) + (c20.x + c22.x);
    P.s1  = S30*((c00.x - c02.x) + (c20.x - c22.x)) + S31*(c10.x - c12.x);
    P.s2  = S30*((c00.x - c20.x) + (c02.x - c22.x)) + S31*(c01.x - c21.x);
    P.u0t = c11.y;
    P.u1t = (c01.y + c21.y) + (c10.y + c12.y);
    P.u2t = (c00.y + c02.y) + (c20.y + c22.y);
    return P;
}

__global__ __launch_bounds__(256) void lumen_main(
    const float* __restrict__ x_in, const float* __restrict__ y_out,
    const float* __restrict__ y_tg, double* __restrict__ gacc,
    float* __restrict__ dice_i, float* __restrict__ dice_c)
{
    __shared__ float2 ring[4][PN];   // 10,880 B; aliased as scratch post-loop

    const int tid = threadIdx.x;
    const int b  = blockIdx.z >> 3;              // 8 d-tiles of DC=16
    const int d0 = (blockIdx.z & 7) * DC;
    const int h0 = blockIdx.y * TH;
    const int w0 = blockIdx.x * TW;
    const unsigned base = (unsigned)b * (unsigned)(DIM_D*DIM_H*DIM_W);
    const unsigned PL = DIM_H*DIM_W;
    const int rep = (blockIdx.x + gridDim.x*(blockIdx.y + gridDim.y*blockIdx.z)) & (NREP-1);

    // ---- staging map: thread handles halo elems tid and tid+256 ----
    const int l1v = tid + 256;
    const int dy0 = tid / PW, dx0 = tid - dy0*PW;
    const int dy1 = l1v / PW, dx1 = l1v - dy1*PW;
    const int sgh0 = h0-1+dy0, sgw0 = w0-1+dx0;
    const int sgh1 = h0-1+dy1, sgw1 = w0-1+dx1;
    const bool w1  = (l1v < PN);
    const bool ok0 = ((unsigned)sgh0 < (unsigned)DIM_H) && ((unsigned)sgw0 < (unsigned)DIM_W);
    const bool ok1 = w1 && ((unsigned)sgh1 < (unsigned)DIM_H) && ((unsigned)sgw1 < (unsigned)DIM_W);
    const unsigned soff0 = ok0 ? (unsigned)(sgh0*DIM_W + sgw0) : 0u;
    const unsigned soff1 = ok1 ? (unsigned)(sgh1*DIM_W + sgw1) : 0u;

    float ld_yo0, ld_tg0, ld_yo1, ld_tg1;

    auto LOADP = [&](int p){
        if ((unsigned)p < (unsigned)DIM_D) {       // uniform branch
            const unsigned pb = base + (unsigned)p*PL;
            float a = y_out[pb + soff0], c = y_tg[pb + soff0];
            float e = y_out[pb + soff1], f = y_tg[pb + soff1];
            ld_yo0 = ok0 ? a : -1e30f;  ld_tg0 = ok0 ? c : 0.f;
            ld_yo1 = ok1 ? e : -1e30f;  ld_tg1 = ok1 ? f : 0.f;
        } else {
            ld_yo0 = -1e30f; ld_tg0 = 0.f; ld_yo1 = -1e30f; ld_tg1 = 0.f;
        }
    };
    // yb = sig(200*(sig(yo)-0.5)) ~= sig(50*yo): max |err| ~4e-5, both sides
    // saturate where the cubic term matters. yo=-1e30 -> ex2(+inf) -> rcp = 0.
    auto WRITEP = [&](int slot){
        float yb0 = rcpf_(1.f + ex2(-50.f*LOG2E*ld_yo0));
        ring[slot][tid] = make_float2(yb0, ld_tg0);
        if (w1) {
            float yb1 = rcpf_(1.f + ex2(-50.f*LOG2E*ld_yo1));
            ring[slot][l1v] = make_float2(yb1, ld_tg1);
        }
    };

    const int ty = tid >> 5, tx = tid & 31;
    const int gh = h0 + ty, gw = w0 + tx;
    const unsigned cen = base + (unsigned)(gh*DIM_W + gw);

    const float KC1 = 4.5399929762484854e-05f, KC2 = 7.2135410e-07f, KC3 = 3.0047e-08f;
    const float L0 = -88.f/26.f, L1 = 6.f/26.f, L2 = 3.f/26.f, L3 = 2.f/26.f;
    const float S30 = 47.f/256.f, S31 = 162.f/256.f;

    const float nhh = 2.f - (gh==0) - (gh==DIM_H-1);
    const float nww = 2.f - (gw==0) - (gw==DIM_W-1);
    const float shw = nhh + nww, phw = nhh * nww;
    const float Tn1 = 1.f + KC1*(1.f+shw) + KC2*(shw+phw) + KC3*phw;
    const float Tn2 = 1.f + KC1*(2.f+shw) + KC2*(2.f*shw+phw) + KC3*(2.f*phw);

    // ---- prologue: planes d0-1, d0, d0+1 staged; d0+2 in regs ----
    LOADP(d0-1); WRITEP(3);
    LOADP(d0  ); WRITEP(0);
    LOADP(d0+1); WRITEP(1);
    LOADP(d0+2);
    float xc  = x_in [cen + (unsigned)d0*PL];
    float yoc = y_out[cen + (unsigned)d0*PL];
    __syncthreads();
    Plane PA = calc_plane(ring[3], ty, tx);
    Plane PB = calc_plane(ring[0], ty, tx);

    float a_ce=0, a_tz=0, a_pzt=0, a_itzi=0, a_ipzti=0, a_yp=0, a_ytg=0;
    float a_y1y2=0, a_y1=0;
    float a_yS1=0, a_ySx=0, a_ySxx=0, a_y4S1=0, a_y4Sx=0, a_y4Sxx=0;
    float dIi=0, dCc=0;

    #pragma unroll 4
    for (int i = 0; i < DC; ++i) {
        const int d = d0 + i;
        WRITEP((i+2)&3);                       // plane d+2 from regs
        __syncthreads();
        LOADP(d+3);                            // prefetch plane d+3 (hidden under math)
        const int dn = min(d+1, DIM_D-1);
        float xn  = x_in [cen + (unsigned)dn*PL];
        float yon = y_out[cen + (unsigned)dn*PL];

        Plane PC = calc_plane(ring[(i+1)&3], ty, tx);   // plane d+1

        float sb0 = PA.u0b + PC.u0b, sb1 = PA.u1b + PC.u1b, sb2 = PA.u2b + PC.u2b;
        float st0 = PA.u0t + PC.u0t, st1 = PA.u1t + PC.u1t, st2 = PA.u2t + PC.u2t;
        float acx = PB.u0b + KC1*(PB.u1b + sb0) + KC2*(PB.u2b + sb1) + KC3*sb2;
        float act = PB.u0t + KC1*(PB.u1t + st0) + KC2*(PB.u2t + st1) + KC3*st2;
        float al  = L0*PB.u0b + L1*(PB.u1b + sb0) + L2*(PB.u2b + sb1) + L3*sb2;
        float a1 = S30*(PA.s1 + PC.s1) + S31*PB.s1;
        float a2 = S30*(PA.s2 + PC.s2) + S31*PB.s2;
        float a3 = (S31*S31)*(PA.u0b - PC.u0b) + (S30*S31)*(PA.u1b - PC.u1b)
                 + (S30*S30)*(PA.u2b - PC.u2b);

        float T = (d==0 || d==DIM_D-1) ? Tn1 : Tn2;
        float t   = PB.u0t;
        float ybc = PB.u0b;

        // CE: one exp2 shared between softplus and sigmoid
        float ayo = fabsf(yoc);
        float e1  = ex2(-LOG2E*ayo);
        float inv = rcpf_(1.f + e1);
        float yp  = (yoc >= 0.f) ? inv : (1.f - inv);
        a_ce += fmaxf(yoc, 0.f) - yoc*t + LN2*lg2(1.f + e1);

        dIi += yp*t;
        dCc += yp + t;

        float l2a = lg2(acx + 1e-6f);
        float z   = -0.1f*LN2*l2a;
        a_tz    += t*z;
        a_pzt   += yp      * (-0.1f*LN2)*lg2(act + 1e-6f);
        a_itzi  += (1.f-t) * (-0.1f*LN2)*lg2((T - acx) + 1e-6f);
        a_ipzti += (1.f-yp)* (-0.1f*LN2)*lg2((T - act) + 1e-6f);
        a_yp    += yp;
        a_ytg   += t;

        float y1 = rcpf_(1.f + ex2(fmaf(-200.f*LOG2E, al, 100.f*LOG2E)));
        float y2 = __builtin_amdgcn_sqrtf(a1*a1 + a2*a2 + a3*a3 + 1e-6f);
        a_y1y2 += y1*y2;
        a_y1   += y1;

        float y4 = rcpf_(1.f + ex2(fmaf(20.f, l2a, 28.853900817779268f)));
        a_yS1  += ybc;  a_ySx  += ybc*xc;  a_ySxx  += ybc*xc*xc;
        a_y4S1 += y4;   a_y4Sx += y4*xc;   a_y4Sxx += y4*xc*xc;

        PA = PB; PB = PC; xc = xn; yoc = yon;
    }

    // fold dice across the wave's two ty rows
    dIi += __shfl_xor(dIi, 32);
    dCc += __shfl_xor(dCc, 32);

    float v[15] = {a_ce, a_tz, a_pzt, a_itzi, a_ipzti, a_yp, a_ytg, a_y1y2, a_y1,
                   a_yS1, a_ySx, a_ySxx, a_y4S1, a_y4Sx, a_y4Sxx};
    #pragma unroll
    for (int k = 0; k < 15; ++k) {
        #pragma unroll
        for (int s = 32; s > 0; s >>= 1) v[k] += __shfl_xor(v[k], s);
    }

    __syncthreads();                 // all ring reads complete
    float* sl = (float*)ring;        // alias dead ring
    if (tid < 64) sl[tid] = 0.f;     // [0..31]=dice_i, [32..63]=dice_c
    __syncthreads();

    int wid = tid >> 6, lane = tid & 63;
    if (lane < 32) {
        atomicAdd(&sl[lane],      dIi);
        atomicAdd(&sl[32 + lane], dCc);
    }
    if (lane == 0) {
        #pragma unroll
        for (int k = 0; k < 15; ++k) sl[64 + wid*16 + k] = v[k];
    }
    __syncthreads();

    if (tid < 15) {
        float s = sl[64+tid] + sl[80+tid] + sl[96+tid] + sl[112+tid];
        int gidx = (tid < 9) ? tid : (9 + (tid - 9)*2 + b);
        atomicAdd(&gacc[rep*24 + gidx], (double)s);
    }
    if (tid < 32) {
        atomicAdd(&dice_i[b*DIM_W + w0 + tid], sl[tid]);
        atomicAdd(&dice_c[b*DIM_W + w0 + tid], sl[32 + tid]);
    }
}

__global__ __launch_bounds__(256) void lumen_final(
    const double* __restrict__ gacc,
    const float* __restrict__ dice_i, const float* __restrict__ dice_c,
    const float* __restrict__ gamma_ace, float* __restrict__ out)
{
    __shared__ float red[4];
    __shared__ double gs[24];
    int tid = threadIdx.x;
    if (tid < 24) {
        double sr = 0.0;
        for (int r = 0; r < NREP; ++r) sr += gacc[r*24 + tid];
        gs[tid] = sr;
    }
    float s = 0.f;
    for (int i = tid; i < 2*DIM_W; i += 256) {
        float I = dice_i[i], C = dice_c[i];
        s += 1.f - 2.f*I/(C + 1e-6f);
    }
    #pragma unroll
    for (int sh = 32; sh > 0; sh >>= 1) s += __shfl_xor(s, sh);
    if ((tid & 63) == 0) red[tid >> 6] = s;
    __syncthreads();
    if (tid == 0) {
        double dice_sum = (double)red[0] + red[1] + red[2] + red[3];
        double loss_dice = dice_sum / (2.0*DIM_W);
        const double Nb = (double)DIM_D * DIM_H * DIM_W;
        const double Nt = 2.0 * Nb;
        const double eps = 1e-6;
        double loss_ce = gs[0]/Nt;
        double dl1 = (gs[1]/Nt) / ((gs[6]/Nt) + eps);
        double dl2 = (gs[2]/Nt) / ((gs[5]/Nt) + eps);
        double dl3 = (gs[3]/Nt) / (((Nt - gs[6])/Nt) + eps);
        double dl4 = (gs[4]/Nt) / (((Nt - gs[5])/Nt) + eps);
        double loss_dt = dl1 + dl2 + dl3 + dl4;
        double E1n = 0.0, E2n = 0.0;
        for (int bb = 0; bb < 2; ++bb) {
            double S1 = gs[9+bb],  Sx = gs[11+bb], Sxx = gs[13+bb];
            double l1 = (Sx/Nb) / ((S1/Nb) + eps);
            E1n += Sxx - 2.0*l1*Sx + l1*l1*S1;
            double Q1 = gs[15+bb], Qx = gs[17+bb], Qxx = gs[19+bb];
            double l2 = (Qx/Nb) / ((Q1/Nb) + eps);
            E2n += Qxx - 2.0*l2*Qx + l2*l2*Q1;
        }
        double E1 = (E1n/Nt) / (((gs[9]+gs[10])/Nt) + eps);
        double E2 = (E2n/Nt) / (((gs[15]+gs[16])/Nt) + eps);
        double S  = (gs[7]/Nt) / ((gs[8]/Nt) + eps);
        double loss_ace = E1 + E2 + (double)gamma_ace[0]*S;
        out[0] = (float)(loss_ce + loss_dice + 0.1*loss_dt + 0.1*loss_ace);
    }
}

extern "C" void kernel_launch(void* const* d_in, const int* in_sizes, int n_in,
                              void* d_out, int out_size, void* d_ws, size_t ws_size,
                              hipStream_t stream) {
    const float* x_in  = (const float*)d_in[0];
    const float* y_out = (const float*)d_in[1];
    const float* y_tg  = (const float*)d_in[2];
    const float* gamma = (const float*)d_in[4];
    float* out = (float*)d_out;

    double* gacc  = (double*)d_ws;                       // 16 replicas x 24 doubles = 3072 B
    float* dice_i = (float*)((char*)d_ws + 4096);        // 384 floats
    float* dice_c = (float*)((char*)d_ws + 6144);        // 384 floats

    hipMemsetAsync(d_ws, 0, 8192, stream);

    dim3 grid(DIM_W/TW, DIM_H/TH, 2*(DIM_D/DC));
    lumen_main<<<grid, 256, 0, stream>>>(x_in, y_out, y_tg, gacc, dice_i, dice_c);
    lumen_final<<<1, 256, 0, stream>>>(gacc, dice_i, dice_c, gamma, out);
}